// Round 2
// baseline (346.697 us; speedup 1.0000x reference)
//
#include <hip/hip_runtime.h>
#include <hip/hip_bf16.h>

typedef __attribute__((ext_vector_type(8))) short bf16x8;
typedef __attribute__((ext_vector_type(4))) float f32x4;

#define KDIM 512
#define NDIM 512
#define BM 128   // block rows = 4 waves x 32
#define BN 128   // block cols (all waves)
#define WROWS 32
#define BK 64
#define NT (KDIM / BK) // 8

__device__ __forceinline__ unsigned int pack_bf16(float a, float b) {
  // exact small integers in f32 -> low 16 mantissa bits are zero, truncation exact
  return (__builtin_bit_cast(unsigned int, a) >> 16) |
         (__builtin_bit_cast(unsigned int, b) & 0xffff0000u);
}

// ---------------- weight quantization + fragment-reorder (512 rows, 1 wave each) ----
// Wq_arr layout: slot s = ((nc*16 + kt)*64 + lane), 8 bf16 per slot, where
// lane holds col = nc*16 + (lane&15), k = kt*32 + (lane>>4)*8 + e  (MFMA B-frag order)
__global__ __launch_bounds__(64)
void quant_w_kernel(const float* __restrict__ W, const float* __restrict__ bias,
                    const float* __restrict__ scale_x,
                    ushort* __restrict__ Wq_arr, float* __restrict__ bq,
                    float* __restrict__ so_out) {
  const int n = blockIdx.x; // output channel = GEMM col
  const int l = threadIdx.x;
  const float* row = W + (size_t)n * KDIM;
  float4 v0 = *(const float4*)(row + l * 8);
  float4 v1 = *(const float4*)(row + l * 8 + 4);
  float m = fmaxf(fmaxf(fmaxf(fabsf(v0.x), fabsf(v0.y)), fmaxf(fabsf(v0.z), fabsf(v0.w))),
                  fmaxf(fmaxf(fabsf(v1.x), fabsf(v1.y)), fmaxf(fabsf(v1.z), fabsf(v1.w))));
#pragma unroll
  for (int off = 32; off; off >>= 1) m = fmaxf(m, __shfl_xor(m, off, 64));
  const float scale = fmaxf(m, 1e-8f) / 127.0f;
  float vals[8] = {v0.x, v0.y, v0.z, v0.w, v1.x, v1.y, v1.z, v1.w};
  unsigned int packed[4];
#pragma unroll
  for (int i = 0; i < 4; ++i) {
    float qa = fminf(fmaxf(rintf(vals[2 * i] / scale), -128.f), 127.f);
    float qb = fminf(fmaxf(rintf(vals[2 * i + 1] / scale), -128.f), 127.f);
    packed[i] = pack_bf16(qa, qb);
  }
  // this lane covers k = l*8 .. l*8+7  ->  kt = l>>2, frag-lane = (n&15) + (l&3)*16
  const size_t slot = ((size_t)(n >> 4) * 16 + (l >> 2)) * 64 + (n & 15) + (l & 3) * 16;
  *(uint4*)(Wq_arr + slot * 8) = make_uint4(packed[0], packed[1], packed[2], packed[3]);
  if (l == 0) {
    float so = scale * scale_x[0];
    so_out[n] = so;
    bq[n] = rintf(bias[n] / so);
  }
}

// ---------------- barrier-free GEMM: wave-private A staging, B direct from L1/L2 ----
__global__ __launch_bounds__(256, 3)
void gemm_kernel(const float* __restrict__ X, const ushort* __restrict__ Wqa,
                 const float* __restrict__ bq, float* __restrict__ Out) {
  __shared__ __align__(16) char smem[4][8192]; // per-wave: 2x4KB A dbuf; reused as 8KB f32 epilogue

  const int nblk = gridDim.x;
  int swz = blockIdx.x;
  if ((nblk & 7) == 0) // XCD-chunked bijective swizzle (T1)
    swz = (blockIdx.x & 7) * (nblk >> 3) + (blockIdx.x >> 3);
  const int bm = swz >> 2;
  const int bn = swz & 3;

  const int tid = threadIdx.x;
  const int l = tid & 63, w = tid >> 6;
  const int lr = l & 15, lk = l >> 4;

  const int wrow0 = bm * BM + w * WROWS;
  const float* xbase = X + (size_t)wrow0 * KDIM;
  char* sA = smem[w]; // wave-private

  f32x4 acc[2][8]; // [mf][nf]
#pragma unroll
  for (int i = 0; i < 2; ++i)
#pragma unroll
    for (int j = 0; j < 8; ++j) acc[i][j] = (f32x4){0.f, 0.f, 0.f, 0.f};

  float4 raw[8]; // 32 rows x 64 k f32 per K-step, 128B/lane, coalesced
  auto gloadA = [&](int t) {
#pragma unroll
    for (int i = 0; i < 8; ++i)
      raw[i] = *(const float4*)(xbase + (size_t)(i * 4 + lk) * KDIM + t * BK + lr * 4);
  };
  auto packwrite = [&](char* buf) { // f32->bf16, r268 XOR-swizzled ds_write_b64
#pragma unroll
    for (int i = 0; i < 8; ++i) {
      int lrow = i * 4 + lk;
      int byteo = (lrow * 128 + lr * 8) ^ ((lrow & 7) << 4);
      uint2 p;
      p.x = pack_bf16(raw[i].x, raw[i].y);
      p.y = pack_bf16(raw[i].z, raw[i].w);
      *(uint2*)(buf + byteo) = p;
    }
  };
  auto readA = [&](const char* buf, int mf, int ks) -> bf16x8 {
    int lrow = mf * 16 + lr;
    int byteo = (lrow * 128 + (ks * 4 + lk) * 16) ^ ((lrow & 7) << 4);
    return *(const bf16x8*)(buf + byteo);
  };

  gloadA(0);
  packwrite(sA);
  gloadA(1);

  for (int t = 0; t < NT; ++t) {
    char* bufc = sA + (t & 1) * 4096;
    char* bufn = sA + ((t + 1) & 1) * 4096;
    bf16x8 af[2][2];
#pragma unroll
    for (int mf = 0; mf < 2; ++mf)
#pragma unroll
      for (int ks = 0; ks < 2; ++ks) af[mf][ks] = readA(bufc, mf, ks);
    if (t < NT - 1) packwrite(bufn); // consumes raw(t+1), overlaps with MFMA below
#pragma unroll
    for (int ks = 0; ks < 2; ++ks) {
      const int kt = t * 2 + ks;
      bf16x8 bf[8];
#pragma unroll
      for (int nf = 0; nf < 8; ++nf) // lane-linear 1KB loads, L1-hot (Wq = 512KB total)
        bf[nf] = *(const bf16x8*)(Wqa + (((size_t)(bn * 8 + nf) * 16 + kt) * 64 + l) * 8);
#pragma unroll
      for (int mf = 0; mf < 2; ++mf)
#pragma unroll
        for (int nf = 0; nf < 8; ++nf)
          acc[mf][nf] = __builtin_amdgcn_mfma_f32_16x16x32_bf16(af[mf][ks], bf[nf],
                                                                acc[mf][nf], 0, 0, 0);
    }
    if (t < NT - 2) gloadA(t + 2); // raw redefined after packwrite consumed it
  }

  // ---- epilogue: bias add + wave-private LDS transpose -> coalesced float4 stores ----
  float bqv[8];
#pragma unroll
  for (int nf = 0; nf < 8; ++nf) bqv[nf] = bq[bn * BN + nf * 16 + lr];

  float* fs = (float*)sA; // 8KB = 16 rows x 128 f32 chunk
#pragma unroll
  for (int mf = 0; mf < 2; ++mf) {
#pragma unroll
    for (int nf = 0; nf < 8; ++nf) {
      const int col = nf * 16 + lr;
#pragma unroll
      for (int e = 0; e < 4; ++e) {
        int r = lk * 4 + e; // C/D layout: row=(lane>>4)*4+reg, col=lane&15 (m89)
        fs[r * 128 + (col ^ ((r & 12) << 2))] = acc[mf][nf][e] + bqv[nf];
      }
    }
#pragma unroll
    for (int j = 0; j < 8; ++j) {
      const int r = j * 2 + (l >> 5);
      const int c4 = (l & 31) * 4;
      f32x4 v = *(const f32x4*)(fs + r * 128 + (c4 ^ ((r & 12) << 2)));
      *(f32x4*)(Out + (size_t)(wrow0 + mf * 16 + r) * NDIM + bn * BN + c4) = v;
    }
  }
}

extern "C" void kernel_launch(void* const* d_in, const int* in_sizes, int n_in,
                              void* d_out, int out_size, void* d_ws, size_t ws_size,
                              hipStream_t stream) {
  const float* x = (const float*)d_in[0];
  const float* weight = (const float*)d_in[1];
  const float* bias = (const float*)d_in[2];
  const float* scale_x = (const float*)d_in[3];
  const int M = in_sizes[0] / KDIM; // 65536

  float* out = (float*)d_out;
  float* so_out = out + (size_t)M * NDIM;
  ushort* Wq_arr = (ushort*)d_ws;
  float* bq = (float*)((char*)d_ws + (size_t)NDIM * KDIM * sizeof(ushort));

  quant_w_kernel<<<NDIM, 64, 0, stream>>>(weight, bias, scale_x, Wq_arr, bq, so_out);

  const int blocks = (M / BM) * (NDIM / BN); // 2048
  gemm_kernel<<<blocks, 256, 0, stream>>>(x, Wq_arr, bq, out);
}